// Round 2
// baseline (80.878 us; speedup 1.0000x reference)
//
#include <hip/hip_runtime.h>
#include <math.h>

#define BEV_H 100
#define BEV_W 100
#define BEV_Z 4
#define N_CAM 6
#define C_DIM 256
#define H_IMG 32
#define W_IMG 88
#define NQ (BEV_H * BEV_W)
#define HW_IMG (H_IMG * W_IMG)   // 2816

// ---------------- Kernel 1: transpose img_feats (cam, C, H, W) -> (cam, H*W, C)
__global__ __launch_bounds__(256) void transpose_kernel(const float* __restrict__ in,
                                                        float* __restrict__ out) {
    __shared__ float tile[32][33];
    int cam = blockIdx.z;
    int hw0 = blockIdx.x * 32;   // 2816 / 32 = 88 blocks
    int c0  = blockIdx.y * 32;   // 256 / 32 = 8 blocks
    int tx = threadIdx.x;        // 0..31 (hw within tile on read)
    int ty = threadIdx.y;        // 0..7
    const float* src = in + (size_t)cam * C_DIM * HW_IMG;
    #pragma unroll
    for (int i = ty; i < 32; i += 8) {
        tile[i][tx] = src[(size_t)(c0 + i) * HW_IMG + hw0 + tx];
    }
    __syncthreads();
    float* dst = out + (size_t)cam * HW_IMG * C_DIM;
    #pragma unroll
    for (int i = ty; i < 32; i += 8) {
        dst[(size_t)(hw0 + i) * C_DIM + c0 + tx] = tile[tx][i];
    }
}

// ---------------- Kernel 2: project + bilinear sample + pool over (cam, z)
// grid: NQ blocks, 256 threads (4 waves). Each wave handles 6 of the 24
// (cam,z) slots; each lane carries 4 channels (float4). LDS cross-wave reduce.
__global__ __launch_bounds__(256) void sample_kernel(const float* __restrict__ imgT,
                                                     const float* __restrict__ l2i,
                                                     float* __restrict__ wbuf) {
    __shared__ float4 sh[4][64];
    int q = blockIdx.x;
    int lane = threadIdx.x & 63;
    int wav  = threadIdx.x >> 6;
    int ix = q % BEV_W;
    int iy = q / BEV_W;
    // match reference expression order: ((i+0.5)/W)*102.4 - 51.2
    float x = ((ix + 0.5f) / (float)BEV_W) * 102.4f - 51.2f;
    float y = ((iy + 0.5f) / (float)BEV_H) * 102.4f - 51.2f;

    float4 acc = make_float4(0.f, 0.f, 0.f, 0.f);

    for (int slot = wav; slot < N_CAM * BEV_Z; slot += 4) {
        int cam = slot >> 2;
        int zi  = slot & 3;
        const float* L = l2i + cam * 16;
        float zl = (zi + 0.5f) * 8.0f - 5.0f;   // reference's unnormalized z
        float cx = L[0] * x + L[1] * y + L[2]  * zl + L[3];
        float cy = L[4] * x + L[5] * y + L[6]  * zl + L[7];
        float cz = L[8] * x + L[9] * y + L[10] * zl + L[11];
        bool valid = cz > 1e-5f;
        float denom = fmaxf(cz, 1e-5f);
        float u = cx / denom;
        float v = cy / denom;
        float gx = (u / (float)W_IMG - 0.5f) * 2.0f;
        float gy = (v / (float)H_IMG - 0.5f) * 2.0f;
        valid = valid && (gx > -1.0f) && (gx < 1.0f) && (gy > -1.0f) && (gy < 1.0f);
        if (!valid) continue;

        // grid_sample coords (align_corners=False): x = (gx+1)*W*0.5 - 0.5
        float xs = (gx + 1.0f) * (float)W_IMG * 0.5f - 0.5f;
        float ys = (gy + 1.0f) * (float)H_IMG * 0.5f - 0.5f;
        float x0f = floorf(xs), y0f = floorf(ys);
        float wx1 = xs - x0f,   wy1 = ys - y0f;
        float wx0 = 1.0f - wx1, wy0 = 1.0f - wy1;
        int x0 = (int)x0f, y0 = (int)y0f;

        const float* base = imgT + (size_t)cam * HW_IMG * C_DIM + lane * 4;
        #pragma unroll
        for (int cnr = 0; cnr < 4; ++cnr) {
            int xi = x0 + (cnr & 1);
            int yi = y0 + (cnr >> 1);
            float wt = ((cnr & 1) ? wx1 : wx0) * ((cnr >> 1) ? wy1 : wy0);
            if (xi < 0 || xi >= W_IMG || yi < 0 || yi >= H_IMG) continue;
            const float4 fv = *(const float4*)(base + (size_t)(yi * W_IMG + xi) * C_DIM);
            acc.x += fv.x * wt;
            acc.y += fv.y * wt;
            acc.z += fv.z * wt;
            acc.w += fv.w * wt;
        }
    }

    sh[wav][lane] = acc;
    __syncthreads();
    if (wav == 0) {
        float4 a = sh[0][lane], b = sh[1][lane], c4 = sh[2][lane], d = sh[3][lane];
        float4 r;
        const float s = 1.0f / 24.0f;
        r.x = (a.x + b.x + c4.x + d.x) * s;
        r.y = (a.y + b.y + c4.y + d.y) * s;
        r.z = (a.z + b.z + c4.z + d.z) * s;
        r.w = (a.w + b.w + c4.w + d.w) * s;
        *(float4*)(wbuf + (size_t)q * C_DIM + lane * 4) = r;
    }
}

// ---------------- Kernel 3: out = w @ W_out^T + b_out + query (f32)
// Block tile 64x64, 256 threads (16x16), 4x4 micro-tile, K-tiles of 32.
#define TM 64
#define TN 64
#define KT 32
__global__ __launch_bounds__(256) void gemm_kernel(const float* __restrict__ wbuf,
                                                   const float* __restrict__ Wout,
                                                   const float* __restrict__ bout,
                                                   const float* __restrict__ query,
                                                   float* __restrict__ out) {
    __shared__ float wT[KT][68];   // [kk][row], pad 68 -> 4-way write conflict only
    __shared__ float Wl[KT][68];   // [kk][col]
    int rb = blockIdx.x * TM;
    int cb = blockIdx.y * TN;
    int t  = threadIdx.x;
    int tc = t & 15, tr = t >> 4;
    int c0 = tc * 4, r0 = tr * 4;

    float acc[4][4] = {};

    for (int kt = 0; kt < C_DIM; kt += KT) {
        #pragma unroll
        for (int i = 0; i < 8; ++i) {
            int e   = i * 256 + t;
            int kk  = e & 31;
            int row = e >> 5;          // 0..63
            float v = 0.0f;
            if (rb + row < NQ) v = wbuf[(size_t)(rb + row) * C_DIM + kt + kk];
            wT[kk][row] = v;
            Wl[kk][row] = Wout[(size_t)(cb + row) * C_DIM + kt + kk];
        }
        __syncthreads();
        #pragma unroll
        for (int kk = 0; kk < KT; ++kk) {
            float4 wv = *(const float4*)&wT[kk][r0];
            float4 Wv = *(const float4*)&Wl[kk][c0];
            float wa[4] = {wv.x, wv.y, wv.z, wv.w};
            float Wa[4] = {Wv.x, Wv.y, Wv.z, Wv.w};
            #pragma unroll
            for (int ii = 0; ii < 4; ++ii)
                #pragma unroll
                for (int jj = 0; jj < 4; ++jj)
                    acc[ii][jj] += wa[ii] * Wa[jj];
        }
        __syncthreads();
    }

    #pragma unroll
    for (int ii = 0; ii < 4; ++ii) {
        int row = rb + r0 + ii;
        if (row >= NQ) continue;
        const float4 bq = *(const float4*)&bout[cb + c0];
        const float4 qv = *(const float4*)&query[(size_t)row * C_DIM + cb + c0];
        float4 o;
        o.x = acc[ii][0] + bq.x + qv.x;
        o.y = acc[ii][1] + bq.y + qv.y;
        o.z = acc[ii][2] + bq.z + qv.z;
        o.w = acc[ii][3] + bq.w + qv.w;
        *(float4*)&out[(size_t)row * C_DIM + cb + c0] = o;
    }
}

extern "C" void kernel_launch(void* const* d_in, const int* in_sizes, int n_in,
                              void* d_out, int out_size, void* d_ws, size_t ws_size,
                              hipStream_t stream) {
    const float* query = (const float*)d_in[0];   // (1, 10000, 256)
    const float* img   = (const float*)d_in[1];   // (1, 6, 256, 32, 88)
    const float* l2i   = (const float*)d_in[2];   // (1, 6, 4, 4)
    const float* Wout  = (const float*)d_in[3];   // (256, 256)
    const float* bout  = (const float*)d_in[4];   // (256,)
    float* out = (float*)d_out;

    float* imgT = (float*)d_ws;                                   // 6*2816*256 f32 = 17,301,504 B
    float* wbuf = (float*)((char*)d_ws + (size_t)N_CAM * HW_IMG * C_DIM * 4);  // 10000*256 f32

    dim3 bT(32, 8);
    dim3 gT(HW_IMG / 32, C_DIM / 32, N_CAM);   // (88, 8, 6)
    transpose_kernel<<<gT, bT, 0, stream>>>(img, imgT);

    sample_kernel<<<NQ, 256, 0, stream>>>(imgT, l2i, wbuf);

    dim3 gG((NQ + TM - 1) / TM, C_DIM / TN);   // (157, 4)
    gemm_kernel<<<gG, 256, 0, stream>>>(wbuf, Wout, bout, query, out);
}

// Round 6
// 52.553 us; speedup vs baseline: 1.5390x; 1.5390x over previous
//
#include <hip/hip_runtime.h>
#include <hip/hip_bf16.h>
#include <math.h>

#define BEV_H 100
#define BEV_W 100
#define BEV_Z 4
#define N_CAM 6
#define C_DIM 256
#define H_IMG 32
#define W_IMG 88
#define NQ (BEV_H * BEV_W)
#define HW_IMG (H_IMG * W_IMG)   // 2816

typedef float f32x4 __attribute__((ext_vector_type(4)));
typedef short short8 __attribute__((ext_vector_type(8)));

__device__ __forceinline__ unsigned short f2b(float f) {
    __hip_bfloat16 h = __float2bfloat16(f);   // RNE
    return *reinterpret_cast<unsigned short*>(&h);
}
__device__ __forceinline__ float b2f(unsigned short u) {
    return __uint_as_float((unsigned int)u << 16);
}

// ---------------- Kernel 1: img (cam,C,H,W) f32 -> imgT (cam,HW,C) bf16 (pure transpose)
__global__ __launch_bounds__(256) void prep_kernel(const float* __restrict__ img,
                                                   unsigned short* __restrict__ imgT) {
    __shared__ unsigned short tile[32][66];   // [hw][c], pad 66 -> conflict-free
    int cam = blockIdx.z;
    int t = threadIdx.x;
    int hw0 = blockIdx.x * 32;                // 88 blocks
    int c0  = blockIdx.y * 64;                // 4 blocks
    const float* src = img + (size_t)cam * C_DIM * HW_IMG;
    #pragma unroll
    for (int e = t; e < 64 * 32; e += 256) {
        int c  = e >> 5;
        int hw = e & 31;
        tile[hw][c] = f2b(src[(size_t)(c0 + c) * HW_IMG + hw0 + hw]);
    }
    __syncthreads();
    unsigned short* dst = imgT + (size_t)cam * HW_IMG * C_DIM;
    #pragma unroll
    for (int e = t; e < 32 * 64; e += 256) {
        int hw = e >> 6;
        int c  = e & 63;
        dst[(size_t)(hw0 + hw) * C_DIM + c0 + c] = tile[hw][c];
    }
}

// ---------------- Kernel 2: project + bilinear + pool. One wave per query, 4 q/block.
// Lane carries channels [lane*4, lane*4+4). No LDS, no syncthreads. Writes bf16 wbuf.
__global__ __launch_bounds__(256) void sample_kernel(const unsigned short* __restrict__ imgT,
                                                     const float* __restrict__ l2i,
                                                     unsigned short* __restrict__ wbuf) {
    int lane = threadIdx.x & 63;
    int wav  = threadIdx.x >> 6;
    int q = blockIdx.x * 4 + wav;
    int ix = q % BEV_W;
    int iy = q / BEV_W;
    float x = ((ix + 0.5f) / (float)BEV_W) * 102.4f - 51.2f;
    float y = ((iy + 0.5f) / (float)BEV_H) * 102.4f - 51.2f;

    float a0 = 0.f, a1 = 0.f, a2 = 0.f, a3 = 0.f;
    const unsigned short* lanebase = imgT + lane * 4;

    for (int cam = 0; cam < N_CAM; ++cam) {
        const float* L = l2i + cam * 16;
        float L0 = L[0], L1 = L[1], L2 = L[2],  L3 = L[3];
        float L4 = L[4], L5 = L[5], L6 = L[6],  L7 = L[7];
        float L8 = L[8], L9 = L[9], L10 = L[10], L11 = L[11];
        const unsigned short* cbase = lanebase + (size_t)cam * HW_IMG * C_DIM;
        #pragma unroll
        for (int zi = 0; zi < BEV_Z; ++zi) {
            float zl = (zi + 0.5f) * 8.0f - 5.0f;   // reference's unnormalized z
            float cx = L0 * x + L1 * y + L2  * zl + L3;
            float cy = L4 * x + L5 * y + L6  * zl + L7;
            float cz = L8 * x + L9 * y + L10 * zl + L11;
            bool valid = cz > 1e-5f;
            float denom = fmaxf(cz, 1e-5f);
            float u = cx / denom;
            float v = cy / denom;
            float gx = (u / (float)W_IMG - 0.5f) * 2.0f;
            float gy = (v / (float)H_IMG - 0.5f) * 2.0f;
            valid = valid && (gx > -1.0f) && (gx < 1.0f) && (gy > -1.0f) && (gy < 1.0f);
            if (!valid) continue;   // wave-uniform branch (q is uniform per wave)

            float xs = (gx + 1.0f) * (float)W_IMG * 0.5f - 0.5f;
            float ys = (gy + 1.0f) * (float)H_IMG * 0.5f - 0.5f;
            float x0f = floorf(xs), y0f = floorf(ys);
            float wx1 = xs - x0f,   wy1 = ys - y0f;
            float wx0 = 1.0f - wx1, wy0 = 1.0f - wy1;
            int x0 = (int)x0f, y0 = (int)y0f;

            #pragma unroll
            for (int cnr = 0; cnr < 4; ++cnr) {
                int xi = x0 + (cnr & 1);
                int yi = y0 + (cnr >> 1);
                float wt = ((cnr & 1) ? wx1 : wx0) * ((cnr >> 1) ? wy1 : wy0);
                if (xi < 0 || xi >= W_IMG || yi < 0 || yi >= H_IMG) continue;
                ushort4 fv = *(const ushort4*)(cbase + (size_t)(yi * W_IMG + xi) * C_DIM);
                a0 += b2f(fv.x) * wt;
                a1 += b2f(fv.y) * wt;
                a2 += b2f(fv.z) * wt;
                a3 += b2f(fv.w) * wt;
            }
        }
    }
    const float s = 1.0f / 24.0f;
    ushort4 o;
    o.x = f2b(a0 * s); o.y = f2b(a1 * s); o.z = f2b(a2 * s); o.w = f2b(a3 * s);
    *(ushort4*)(wbuf + (size_t)q * C_DIM + lane * 4) = o;
}

// ---------------- Kernel 3: out = w @ Wout^T + b + query, bf16 MFMA 16x16x32
// Block 64x64, 4 waves in 2x2, each wave a 32x32 sub-tile (2x2 fragments).
// B (W_out) is read as f32 and converted to bf16 during LDS staging (no ws dep).
#define BM 64
#define BN 64
#define BK 32
__global__ __launch_bounds__(256) void gemm_kernel(const unsigned short* __restrict__ A,   // wbuf bf16 (NQ x 256)
                                                   const float* __restrict__ Wout,         // f32 (256 x 256)
                                                   const float* __restrict__ bout,
                                                   const float* __restrict__ query,
                                                   float* __restrict__ out) {
    __shared__ unsigned short Al[BM][40];   // 80B rows: 16B-aligned b128 reads, 2-way banks (free)
    __shared__ unsigned short Bl[BN][40];
    int rb = blockIdx.x * BM;
    int cb = blockIdx.y * BN;
    int t = threadIdx.x;
    int lane = t & 63;
    int wid = t >> 6;
    int wr = wid >> 1, wc = wid & 1;

    f32x4 acc[2][2] = {};

    int srow = t >> 2;              // 0..63
    int schunk = (t & 3) * 8;       // k element offset (8 elems = 16B bf16 / 32B f32)

    for (int kt = 0; kt < C_DIM; kt += BK) {
        int grow = rb + srow;
        int4 aval = make_int4(0, 0, 0, 0);
        if (grow < NQ) aval = *(const int4*)(A + (size_t)grow * C_DIM + kt + schunk);
        const float* bsrc = Wout + (size_t)(cb + srow) * C_DIM + kt + schunk;
        float4 b0 = *(const float4*)(bsrc);
        float4 b1 = *(const float4*)(bsrc + 4);
        ushort4 blo, bhi;
        blo.x = f2b(b0.x); blo.y = f2b(b0.y); blo.z = f2b(b0.z); blo.w = f2b(b0.w);
        bhi.x = f2b(b1.x); bhi.y = f2b(b1.y); bhi.z = f2b(b1.z); bhi.w = f2b(b1.w);
        *(int4*)(&Al[srow][schunk]) = aval;
        *(ushort4*)(&Bl[srow][schunk])     = blo;
        *(ushort4*)(&Bl[srow][schunk + 4]) = bhi;
        __syncthreads();

        int kg = (lane >> 4) * 8;
        int fr = lane & 15;
        short8 af0 = *(const short8*)(&Al[wr * 32 + fr][kg]);
        short8 af1 = *(const short8*)(&Al[wr * 32 + 16 + fr][kg]);
        short8 bf0 = *(const short8*)(&Bl[wc * 32 + fr][kg]);
        short8 bf1 = *(const short8*)(&Bl[wc * 32 + 16 + fr][kg]);
        acc[0][0] = __builtin_amdgcn_mfma_f32_16x16x32_bf16(af0, bf0, acc[0][0], 0, 0, 0);
        acc[0][1] = __builtin_amdgcn_mfma_f32_16x16x32_bf16(af0, bf1, acc[0][1], 0, 0, 0);
        acc[1][0] = __builtin_amdgcn_mfma_f32_16x16x32_bf16(af1, bf0, acc[1][0], 0, 0, 0);
        acc[1][1] = __builtin_amdgcn_mfma_f32_16x16x32_bf16(af1, bf1, acc[1][1], 0, 0, 0);
        __syncthreads();
    }

    // C/D layout (verified m89/m91): col = lane&15, row = (lane>>4)*4 + reg
    int crow = (lane >> 4) * 4;
    int ccol = lane & 15;
    #pragma unroll
    for (int fi = 0; fi < 2; ++fi) {
        #pragma unroll
        for (int fj = 0; fj < 2; ++fj) {
            int n = cb + wc * 32 + fj * 16 + ccol;
            float bn = bout[n];
            #pragma unroll
            for (int r = 0; r < 4; ++r) {
                int m = rb + wr * 32 + fi * 16 + crow + r;
                if (m < NQ) {
                    size_t off = (size_t)m * C_DIM + n;
                    out[off] = acc[fi][fj][r] + bn + query[off];
                }
            }
        }
    }
}

extern "C" void kernel_launch(void* const* d_in, const int* in_sizes, int n_in,
                              void* d_out, int out_size, void* d_ws, size_t ws_size,
                              hipStream_t stream) {
    const float* query = (const float*)d_in[0];   // (1, 10000, 256)
    const float* img   = (const float*)d_in[1];   // (1, 6, 256, 32, 88)
    const float* l2i   = (const float*)d_in[2];   // (1, 6, 4, 4)
    const float* Wout  = (const float*)d_in[3];   // (256, 256)
    const float* bout  = (const float*)d_in[4];   // (256,)
    float* out = (float*)d_out;

    // workspace layout (16B aligned)
    unsigned short* imgT = (unsigned short*)d_ws;                     // 6*2816*256*2 = 8,650,752 B
    unsigned short* wbuf = (unsigned short*)((char*)d_ws + 8650752);  // 10000*256*2  = 5,120,000 B

    dim3 gP(HW_IMG / 32, C_DIM / 64, N_CAM);   // (88, 4, 6)
    prep_kernel<<<gP, 256, 0, stream>>>(img, imgT);

    sample_kernel<<<NQ / 4, 256, 0, stream>>>(imgT, l2i, wbuf);

    dim3 gG((NQ + BM - 1) / BM, C_DIM / BN);   // (157, 4)
    gemm_kernel<<<gG, 256, 0, stream>>>(wbuf, Wout, bout, query, out);
}

// Round 8
// 38.112 us; speedup vs baseline: 2.1221x; 1.3789x over previous
//
#include <hip/hip_runtime.h>
#include <hip/hip_bf16.h>
#include <math.h>

#define BEV_H 100
#define BEV_W 100
#define BEV_Z 4
#define N_CAM 6
#define C_DIM 256
#define H_IMG 32
#define W_IMG 88
#define NQ (BEV_H * BEV_W)
#define HW_IMG (H_IMG * W_IMG)   // 2816

typedef float f32x4 __attribute__((ext_vector_type(4)));
typedef short short8 __attribute__((ext_vector_type(8)));

__device__ __forceinline__ unsigned short f2b(float f) {
    __hip_bfloat16 h = __float2bfloat16(f);   // RNE
    return *reinterpret_cast<unsigned short*>(&h);
}
__device__ __forceinline__ float b2f(unsigned short u) {
    return __uint_as_float((unsigned int)u << 16);
}

// ---------------- Kernel 1: img (cam,C,H,W) f32 -> imgT (cam,HW,C) bf16
// Vectorized: float4 global reads, ushort4 global writes, LDS transpose.
__global__ __launch_bounds__(256) void prep_kernel(const float* __restrict__ img,
                                                   unsigned short* __restrict__ imgT) {
    __shared__ unsigned short tile[32][68];   // [hw][c], pad 68 keeps ushort4 reads clean
    int cam = blockIdx.z;
    int t = threadIdx.x;
    int hw0 = blockIdx.x * 32;                // 88 blocks
    int c0  = blockIdx.y * 64;                // 4 blocks
    const float* src = img + (size_t)cam * C_DIM * HW_IMG;
    #pragma unroll
    for (int i = 0; i < 2; ++i) {
        int e = i * 256 + t;                  // 0..511
        int c  = e >> 3;                      // 0..63
        int hq = e & 7;                       // hw quad
        float4 v = *(const float4*)(src + (size_t)(c0 + c) * HW_IMG + hw0 + hq * 4);
        tile[hq * 4 + 0][c] = f2b(v.x);
        tile[hq * 4 + 1][c] = f2b(v.y);
        tile[hq * 4 + 2][c] = f2b(v.z);
        tile[hq * 4 + 3][c] = f2b(v.w);
    }
    __syncthreads();
    unsigned short* dst = imgT + (size_t)cam * HW_IMG * C_DIM;
    #pragma unroll
    for (int i = 0; i < 2; ++i) {
        int e = i * 256 + t;
        int hw = e >> 4;                      // 0..31
        int cq = e & 15;                      // c quad
        ushort4 o;
        o.x = tile[hw][cq * 4 + 0];
        o.y = tile[hw][cq * 4 + 1];
        o.z = tile[hw][cq * 4 + 2];
        o.w = tile[hw][cq * 4 + 3];
        *(ushort4*)(dst + (size_t)(hw0 + hw) * C_DIM + c0 + cq * 4) = o;
    }
}

// ---------------- Kernel 2: project + bilinear + pool. One wave per query, 4 q/block.
// Hoisted per-cam projection base, v_rcp instead of IEEE div, direct u/v bounds.
__global__ __launch_bounds__(256) void sample_kernel(const unsigned short* __restrict__ imgT,
                                                     const float* __restrict__ l2i,
                                                     unsigned short* __restrict__ wbuf) {
    int lane = threadIdx.x & 63;
    int wav  = threadIdx.x >> 6;
    int q = blockIdx.x * 4 + wav;
    int ix = q % BEV_W;
    int iy = q / BEV_W;
    float x = ((ix + 0.5f) / (float)BEV_W) * 102.4f - 51.2f;
    float y = ((iy + 0.5f) / (float)BEV_H) * 102.4f - 51.2f;

    float a0 = 0.f, a1 = 0.f, a2 = 0.f, a3 = 0.f;
    const unsigned short* lanebase = imgT + lane * 4;

    for (int cam = 0; cam < N_CAM; ++cam) {
        const float* L = l2i + cam * 16;
        float L2 = L[2], L6 = L[6], L10 = L[10];
        float bx = fmaf(L[0], x, fmaf(L[1], y, L[3]));
        float by = fmaf(L[4], x, fmaf(L[5], y, L[7]));
        float bz = fmaf(L[8], x, fmaf(L[9], y, L[11]));
        const unsigned short* cbase = lanebase + (size_t)cam * HW_IMG * C_DIM;
        #pragma unroll
        for (int zi = 0; zi < BEV_Z; ++zi) {
            float zl = (zi + 0.5f) * 8.0f - 5.0f;   // reference's unnormalized z
            float cx = fmaf(L2, zl, bx);
            float cy = fmaf(L6, zl, by);
            float cz = fmaf(L10, zl, bz);
            float denom = fmaxf(cz, 1e-5f);
            float inv = __builtin_amdgcn_rcpf(denom);
            float u = cx * inv;
            float v = cy * inv;
            // (gx>-1 && gx<1) <=> u in (0, 88); (gy>-1 && gy<1) <=> v in (0, 32)
            bool valid = (cz > 1e-5f) && (u > 0.f) && (u < (float)W_IMG)
                                      && (v > 0.f) && (v < (float)H_IMG);
            if (!valid) continue;   // wave-uniform branch (q uniform per wave)

            // xs = (gx+1)*W/2 - 0.5 == u - 0.5 exactly
            float xs = u - 0.5f;
            float ys = v - 0.5f;
            float x0f = floorf(xs), y0f = floorf(ys);
            float wx1 = xs - x0f,   wy1 = ys - y0f;
            float wx0 = 1.0f - wx1, wy0 = 1.0f - wy1;
            int x0 = (int)x0f, y0 = (int)y0f;

            #pragma unroll
            for (int cnr = 0; cnr < 4; ++cnr) {
                int xi = x0 + (cnr & 1);
                int yi = y0 + (cnr >> 1);
                float wt = ((cnr & 1) ? wx1 : wx0) * ((cnr >> 1) ? wy1 : wy0);
                if (xi < 0 || xi >= W_IMG || yi < 0 || yi >= H_IMG) continue;
                ushort4 fv = *(const ushort4*)(cbase + (size_t)(yi * W_IMG + xi) * C_DIM);
                a0 += b2f(fv.x) * wt;
                a1 += b2f(fv.y) * wt;
                a2 += b2f(fv.z) * wt;
                a3 += b2f(fv.w) * wt;
            }
        }
    }
    const float s = 1.0f / 24.0f;
    ushort4 o;
    o.x = f2b(a0 * s); o.y = f2b(a1 * s); o.z = f2b(a2 * s); o.w = f2b(a3 * s);
    *(ushort4*)(wbuf + (size_t)q * C_DIM + lane * 4) = o;
}

// ---------------- Kernel 3: out = w @ Wout^T + b + query, bf16 MFMA 16x16x32
// Block 64x64, 4 waves 2x2. BK=128 (2 stages), XOR-swizzled LDS (T2), 4 barriers.
// FIX (R7): staging now covers all 16 chunks/row (was 8 -> read uninit LDS -> NaN).
#define BM 64
#define BN 64
#define BKK 128
__global__ __launch_bounds__(256) void gemm_kernel(const unsigned short* __restrict__ A,   // wbuf bf16 (NQ x 256)
                                                   const float* __restrict__ Wout,         // f32 (256 x 256)
                                                   const float* __restrict__ bout,
                                                   const float* __restrict__ query,
                                                   float* __restrict__ out) {
    __shared__ unsigned short Al[BM * BKK];   // 16 KB, swizzled: byte ^= (row&7)<<4
    __shared__ unsigned short Bl[BN * BKK];   // 16 KB
    int rb = blockIdx.x * BM;
    int cb = blockIdx.y * BN;
    int t = threadIdx.x;
    int lane = t & 63;
    int wid = t >> 6;
    int wr = wid >> 1, wc = wid & 1;
    int fr = lane & 15;
    int kq = lane >> 4;                       // 0..3: k-group within K=32

    f32x4 acc[2][2] = {};

    for (int kt = 0; kt < C_DIM; kt += BKK) {
        // stage A: 64 rows x 128 k (bf16) = 1024 x 16B chunks
        #pragma unroll
        for (int i = 0; i < 4; ++i) {
            int idx = i * 256 + t;            // 0..1023
            int row = idx >> 4;               // 0..63
            int ch  = idx & 15;               // 16B chunk within 256B row
            int4 av = make_int4(0, 0, 0, 0);
            int grow = rb + row;
            if (grow < NQ) av = *(const int4*)(A + (size_t)grow * C_DIM + kt + ch * 8);
            int off = (row * 256 + ch * 16) ^ ((row & 7) << 4);
            *(int4*)((char*)Al + off) = av;
        }
        // stage B: read f32, convert to bf16 (1024 chunks)
        #pragma unroll
        for (int i = 0; i < 4; ++i) {
            int idx = i * 256 + t;
            int row = idx >> 4;
            int ch  = idx & 15;
            const float* bs = Wout + (size_t)(cb + row) * C_DIM + kt + ch * 8;
            float4 b0 = *(const float4*)(bs);
            float4 b1 = *(const float4*)(bs + 4);
            ushort4 plo, phi;
            plo.x = f2b(b0.x); plo.y = f2b(b0.y); plo.z = f2b(b0.z); plo.w = f2b(b0.w);
            phi.x = f2b(b1.x); phi.y = f2b(b1.y); phi.z = f2b(b1.z); phi.w = f2b(b1.w);
            int off = (row * 256 + ch * 16) ^ ((row & 7) << 4);
            *(ushort4*)((char*)Bl + off)     = plo;
            *(ushort4*)((char*)Bl + off + 8) = phi;
        }
        __syncthreads();

        #pragma unroll
        for (int ks = 0; ks < 4; ++ks) {
            int kbyte = ks * 64 + kq * 16;
            int ra0 = wr * 32 + fr, ra1 = ra0 + 16;
            int rb0 = wc * 32 + fr, rb1 = rb0 + 16;
            short8 af0 = *(const short8*)((const char*)Al + ((ra0 * 256 + kbyte) ^ ((ra0 & 7) << 4)));
            short8 af1 = *(const short8*)((const char*)Al + ((ra1 * 256 + kbyte) ^ ((ra1 & 7) << 4)));
            short8 bf0 = *(const short8*)((const char*)Bl + ((rb0 * 256 + kbyte) ^ ((rb0 & 7) << 4)));
            short8 bf1 = *(const short8*)((const char*)Bl + ((rb1 * 256 + kbyte) ^ ((rb1 & 7) << 4)));
            acc[0][0] = __builtin_amdgcn_mfma_f32_16x16x32_bf16(af0, bf0, acc[0][0], 0, 0, 0);
            acc[0][1] = __builtin_amdgcn_mfma_f32_16x16x32_bf16(af0, bf1, acc[0][1], 0, 0, 0);
            acc[1][0] = __builtin_amdgcn_mfma_f32_16x16x32_bf16(af1, bf0, acc[1][0], 0, 0, 0);
            acc[1][1] = __builtin_amdgcn_mfma_f32_16x16x32_bf16(af1, bf1, acc[1][1], 0, 0, 0);
        }
        __syncthreads();
    }

    // C/D layout (verified m89/m91): col = lane&15, row = (lane>>4)*4 + reg
    int crow = (lane >> 4) * 4;
    int ccol = lane & 15;
    #pragma unroll
    for (int fi = 0; fi < 2; ++fi) {
        #pragma unroll
        for (int fj = 0; fj < 2; ++fj) {
            int n = cb + wc * 32 + fj * 16 + ccol;
            float bn = bout[n];
            #pragma unroll
            for (int r = 0; r < 4; ++r) {
                int m = rb + wr * 32 + fi * 16 + crow + r;
                if (m < NQ) {
                    size_t off = (size_t)m * C_DIM + n;
                    out[off] = acc[fi][fj][r] + bn + query[off];
                }
            }
        }
    }
}

extern "C" void kernel_launch(void* const* d_in, const int* in_sizes, int n_in,
                              void* d_out, int out_size, void* d_ws, size_t ws_size,
                              hipStream_t stream) {
    const float* query = (const float*)d_in[0];   // (1, 10000, 256)
    const float* img   = (const float*)d_in[1];   // (1, 6, 256, 32, 88)
    const float* l2i   = (const float*)d_in[2];   // (1, 6, 4, 4)
    const float* Wout  = (const float*)d_in[3];   // (256, 256)
    const float* bout  = (const float*)d_in[4];   // (256,)
    float* out = (float*)d_out;

    // workspace layout (16B aligned)
    unsigned short* imgT = (unsigned short*)d_ws;                     // 6*2816*256*2 = 8,650,752 B
    unsigned short* wbuf = (unsigned short*)((char*)d_ws + 8650752);  // 10000*256*2  = 5,120,000 B

    dim3 gP(HW_IMG / 32, C_DIM / 64, N_CAM);   // (88, 4, 6)
    prep_kernel<<<gP, 256, 0, stream>>>(img, imgT);

    sample_kernel<<<NQ / 4, 256, 0, stream>>>(imgT, l2i, wbuf);

    dim3 gG((NQ + BM - 1) / BM, C_DIM / BN);   // (157, 4)
    gemm_kernel<<<gG, 256, 0, stream>>>(wbuf, Wout, bout, query, out);
}

// Round 9
// 29.837 us; speedup vs baseline: 2.7107x; 1.2773x over previous
//
#include <hip/hip_runtime.h>
#include <hip/hip_bf16.h>
#include <math.h>

#define BEV_H 100
#define BEV_W 100
#define BEV_Z 4
#define N_CAM 6
#define C_DIM 256
#define H_IMG 32
#define W_IMG 88
#define NQ (BEV_H * BEV_W)
#define HW_IMG (H_IMG * W_IMG)   // 2816

typedef float f32x4 __attribute__((ext_vector_type(4)));
typedef short short8 __attribute__((ext_vector_type(8)));

__device__ __forceinline__ unsigned short f2b(float f) {
    __hip_bfloat16 h = __float2bfloat16(f);   // RNE
    return *reinterpret_cast<unsigned short*>(&h);
}
__device__ __forceinline__ float b2f(unsigned short u) {
    return __uint_as_float((unsigned int)u << 16);
}

// ---------------- Kernel 1: img (cam,C,H,W) f32 -> imgT (cam,HW,C) bf16
// Vectorized: float4 global reads, ushort4 global writes, LDS transpose.
__global__ __launch_bounds__(256) void prep_kernel(const float* __restrict__ img,
                                                   unsigned short* __restrict__ imgT) {
    __shared__ unsigned short tile[32][68];   // [hw][c], pad 68 keeps ushort4 reads clean
    int cam = blockIdx.z;
    int t = threadIdx.x;
    int hw0 = blockIdx.x * 32;                // 88 blocks
    int c0  = blockIdx.y * 64;                // 4 blocks
    const float* src = img + (size_t)cam * C_DIM * HW_IMG;
    #pragma unroll
    for (int i = 0; i < 2; ++i) {
        int e = i * 256 + t;                  // 0..511
        int c  = e >> 3;                      // 0..63
        int hq = e & 7;                       // hw quad
        float4 v = *(const float4*)(src + (size_t)(c0 + c) * HW_IMG + hw0 + hq * 4);
        tile[hq * 4 + 0][c] = f2b(v.x);
        tile[hq * 4 + 1][c] = f2b(v.y);
        tile[hq * 4 + 2][c] = f2b(v.z);
        tile[hq * 4 + 3][c] = f2b(v.w);
    }
    __syncthreads();
    unsigned short* dst = imgT + (size_t)cam * HW_IMG * C_DIM;
    #pragma unroll
    for (int i = 0; i < 2; ++i) {
        int e = i * 256 + t;
        int hw = e >> 4;                      // 0..31
        int cq = e & 15;                      // c quad
        ushort4 o;
        o.x = tile[hw][cq * 4 + 0];
        o.y = tile[hw][cq * 4 + 1];
        o.z = tile[hw][cq * 4 + 2];
        o.w = tile[hw][cq * 4 + 3];
        *(ushort4*)(dst + (size_t)(hw0 + hw) * C_DIM + c0 + cq * 4) = o;
    }
}

// ---------------- Kernel 2: project + bilinear + pool, two-phase.
// Block = 4 queries, 256 threads. Phase 1: 128 threads compute one (q,slot)
// projection each; valid slots compacted into LDS via deterministic
// ballot-prefix (slot order preserved -> same accumulation order every call).
// Phase 2: wave w walks query w's valid entries (broadcast LDS reads) and
// does the 4 ushort4 corner gathers + FMAs. OOB corners: clamped offset,
// zero weight (== reference's clip + w*valid semantics).
__global__ __launch_bounds__(256) void sample_kernel(const unsigned short* __restrict__ imgT,
                                                     const float* __restrict__ l2i,
                                                     unsigned short* __restrict__ wbuf) {
    __shared__ int   ent_off[4][24][4];
    __shared__ float ent_w[4][24][4];
    __shared__ int   counts[4];
    int t = threadIdx.x;

    if (t < 128) {
        int ql   = t >> 5;        // 0..3
        int slot = t & 31;        // 0..31; slots 24..31 are padding
        int q = blockIdx.x * 4 + ql;
        int ix = q % BEV_W;
        int iy = q / BEV_W;
        float x = ((ix + 0.5f) / (float)BEV_W) * 102.4f - 51.2f;
        float y = ((iy + 0.5f) / (float)BEV_H) * 102.4f - 51.2f;

        bool valid = false;
        int   o0 = 0, o1 = 0, o2 = 0, o3 = 0;
        float w0 = 0.f, w1 = 0.f, w2 = 0.f, w3 = 0.f;
        if (slot < 24) {
            int cam = slot >> 2;
            int zi  = slot & 3;
            const float* L = l2i + cam * 16;
            float zl = (zi + 0.5f) * 8.0f - 5.0f;   // reference's unnormalized z
            float cx = fmaf(L[0], x, fmaf(L[1], y, fmaf(L[2],  zl, L[3])));
            float cy = fmaf(L[4], x, fmaf(L[5], y, fmaf(L[6],  zl, L[7])));
            float cz = fmaf(L[8], x, fmaf(L[9], y, fmaf(L[10], zl, L[11])));
            float denom = fmaxf(cz, 1e-5f);
            float inv = __builtin_amdgcn_rcpf(denom);
            float u = cx * inv;
            float v = cy * inv;
            // (gx>-1 && gx<1) <=> u in (0,88); (gy>-1 && gy<1) <=> v in (0,32)
            if ((cz > 1e-5f) && (u > 0.f) && (u < (float)W_IMG)
                             && (v > 0.f) && (v < (float)H_IMG)) {
                valid = true;
                float xs = u - 0.5f;    // == (gx+1)*W/2 - 0.5 exactly
                float ys = v - 0.5f;
                float x0f = floorf(xs), y0f = floorf(ys);
                float wx1 = xs - x0f,   wy1 = ys - y0f;
                float wx0 = 1.0f - wx1, wy0 = 1.0f - wy1;
                int x0 = (int)x0f, y0 = (int)y0f;   // x0 in [-1,87], y0 in [-1,31]
                int x1 = x0 + 1,   y1 = y0 + 1;
                float mxl = (x0 >= 0)     ? 1.f : 0.f;
                float mxh = (x1 < W_IMG)  ? 1.f : 0.f;
                float myl = (y0 >= 0)     ? 1.f : 0.f;
                float myh = (y1 < H_IMG)  ? 1.f : 0.f;
                int x0c = max(x0, 0), x1c = min(x1, W_IMG - 1);
                int y0c = max(y0, 0), y1c = min(y1, H_IMG - 1);
                int cbase = cam * HW_IMG;
                // byte offsets into imgT (row stride C_DIM*2 = 512 = <<9)
                o0 = (cbase + y0c * W_IMG + x0c) << 9;  w0 = (wx0 * mxl) * (wy0 * myl);
                o1 = (cbase + y0c * W_IMG + x1c) << 9;  w1 = (wx1 * mxh) * (wy0 * myl);
                o2 = (cbase + y1c * W_IMG + x0c) << 9;  w2 = (wx0 * mxl) * (wy1 * myh);
                o3 = (cbase + y1c * W_IMG + x1c) << 9;  w3 = (wx1 * mxh) * (wy1 * myh);
            }
        }
        unsigned long long bal = __ballot(valid);
        unsigned int half = (t & 32) ? (unsigned int)(bal >> 32) : (unsigned int)bal;
        int lane32 = t & 31;
        int pre = __popc(half & ((1u << lane32) - 1u));
        if (valid) {
            ent_off[ql][pre][0] = o0; ent_off[ql][pre][1] = o1;
            ent_off[ql][pre][2] = o2; ent_off[ql][pre][3] = o3;
            ent_w[ql][pre][0] = w0; ent_w[ql][pre][1] = w1;
            ent_w[ql][pre][2] = w2; ent_w[ql][pre][3] = w3;
        }
        if (lane32 == 0) counts[ql] = __popc(half);
    }
    __syncthreads();

    int wav  = t >> 6;
    int lane = t & 63;
    int q = blockIdx.x * 4 + wav;
    int cnt = counts[wav];
    const char* base = (const char*)imgT + lane * 8;   // 4 channels/lane

    float a0 = 0.f, a1 = 0.f, a2 = 0.f, a3 = 0.f;
    for (int i = 0; i < cnt; ++i) {
        int4   offs = *(const int4*)(&ent_off[wav][i][0]);    // broadcast
        float4 wv   = *(const float4*)(&ent_w[wav][i][0]);    // broadcast
        ushort4 f0 = *(const ushort4*)(base + offs.x);
        ushort4 f1 = *(const ushort4*)(base + offs.y);
        ushort4 f2 = *(const ushort4*)(base + offs.z);
        ushort4 f3 = *(const ushort4*)(base + offs.w);
        a0 += b2f(f0.x) * wv.x; a1 += b2f(f0.y) * wv.x;
        a2 += b2f(f0.z) * wv.x; a3 += b2f(f0.w) * wv.x;
        a0 += b2f(f1.x) * wv.y; a1 += b2f(f1.y) * wv.y;
        a2 += b2f(f1.z) * wv.y; a3 += b2f(f1.w) * wv.y;
        a0 += b2f(f2.x) * wv.z; a1 += b2f(f2.y) * wv.z;
        a2 += b2f(f2.z) * wv.z; a3 += b2f(f2.w) * wv.z;
        a0 += b2f(f3.x) * wv.w; a1 += b2f(f3.y) * wv.w;
        a2 += b2f(f3.z) * wv.w; a3 += b2f(f3.w) * wv.w;
    }
    const float s = 1.0f / 24.0f;
    ushort4 o;
    o.x = f2b(a0 * s); o.y = f2b(a1 * s); o.z = f2b(a2 * s); o.w = f2b(a3 * s);
    *(ushort4*)(wbuf + (size_t)q * C_DIM + lane * 4) = o;
}

// ---------------- Kernel 3: out = w @ Wout^T + b + query, bf16 MFMA 16x16x32
// Block 64x64, 4 waves 2x2. BK=128 (2 stages), XOR-swizzled LDS (T2), 4 barriers.
#define BM 64
#define BN 64
#define BKK 128
__global__ __launch_bounds__(256) void gemm_kernel(const unsigned short* __restrict__ A,   // wbuf bf16 (NQ x 256)
                                                   const float* __restrict__ Wout,         // f32 (256 x 256)
                                                   const float* __restrict__ bout,
                                                   const float* __restrict__ query,
                                                   float* __restrict__ out) {
    __shared__ unsigned short Al[BM * BKK];   // 16 KB, swizzled: byte ^= (row&7)<<4
    __shared__ unsigned short Bl[BN * BKK];   // 16 KB
    int rb = blockIdx.x * BM;
    int cb = blockIdx.y * BN;
    int t = threadIdx.x;
    int lane = t & 63;
    int wid = t >> 6;
    int wr = wid >> 1, wc = wid & 1;
    int fr = lane & 15;
    int kq = lane >> 4;                       // 0..3: k-group within K=32

    f32x4 acc[2][2] = {};

    for (int kt = 0; kt < C_DIM; kt += BKK) {
        // stage A: 64 rows x 128 k (bf16) = 1024 x 16B chunks
        #pragma unroll
        for (int i = 0; i < 4; ++i) {
            int idx = i * 256 + t;            // 0..1023
            int row = idx >> 4;               // 0..63
            int ch  = idx & 15;               // 16B chunk within 256B row
            int4 av = make_int4(0, 0, 0, 0);
            int grow = rb + row;
            if (grow < NQ) av = *(const int4*)(A + (size_t)grow * C_DIM + kt + ch * 8);
            int off = (row * 256 + ch * 16) ^ ((row & 7) << 4);
            *(int4*)((char*)Al + off) = av;
        }
        // stage B: read f32, convert to bf16 (1024 chunks)
        #pragma unroll
        for (int i = 0; i < 4; ++i) {
            int idx = i * 256 + t;
            int row = idx >> 4;
            int ch  = idx & 15;
            const float* bs = Wout + (size_t)(cb + row) * C_DIM + kt + ch * 8;
            float4 b0 = *(const float4*)(bs);
            float4 b1 = *(const float4*)(bs + 4);
            ushort4 plo, phi;
            plo.x = f2b(b0.x); plo.y = f2b(b0.y); plo.z = f2b(b0.z); plo.w = f2b(b0.w);
            phi.x = f2b(b1.x); phi.y = f2b(b1.y); phi.z = f2b(b1.z); phi.w = f2b(b1.w);
            int off = (row * 256 + ch * 16) ^ ((row & 7) << 4);
            *(ushort4*)((char*)Bl + off)     = plo;
            *(ushort4*)((char*)Bl + off + 8) = phi;
        }
        __syncthreads();

        #pragma unroll
        for (int ks = 0; ks < 4; ++ks) {
            int kbyte = ks * 64 + kq * 16;
            int ra0 = wr * 32 + fr, ra1 = ra0 + 16;
            int rb0 = wc * 32 + fr, rb1 = rb0 + 16;
            short8 af0 = *(const short8*)((const char*)Al + ((ra0 * 256 + kbyte) ^ ((ra0 & 7) << 4)));
            short8 af1 = *(const short8*)((const char*)Al + ((ra1 * 256 + kbyte) ^ ((ra1 & 7) << 4)));
            short8 bf0 = *(const short8*)((const char*)Bl + ((rb0 * 256 + kbyte) ^ ((rb0 & 7) << 4)));
            short8 bf1 = *(const short8*)((const char*)Bl + ((rb1 * 256 + kbyte) ^ ((rb1 & 7) << 4)));
            acc[0][0] = __builtin_amdgcn_mfma_f32_16x16x32_bf16(af0, bf0, acc[0][0], 0, 0, 0);
            acc[0][1] = __builtin_amdgcn_mfma_f32_16x16x32_bf16(af0, bf1, acc[0][1], 0, 0, 0);
            acc[1][0] = __builtin_amdgcn_mfma_f32_16x16x32_bf16(af1, bf0, acc[1][0], 0, 0, 0);
            acc[1][1] = __builtin_amdgcn_mfma_f32_16x16x32_bf16(af1, bf1, acc[1][1], 0, 0, 0);
        }
        __syncthreads();
    }

    // C/D layout (verified m89/m91): col = lane&15, row = (lane>>4)*4 + reg
    int crow = (lane >> 4) * 4;
    int ccol = lane & 15;
    #pragma unroll
    for (int fi = 0; fi < 2; ++fi) {
        #pragma unroll
        for (int fj = 0; fj < 2; ++fj) {
            int n = cb + wc * 32 + fj * 16 + ccol;
            float bn = bout[n];
            #pragma unroll
            for (int r = 0; r < 4; ++r) {
                int m = rb + wr * 32 + fi * 16 + crow + r;
                if (m < NQ) {
                    size_t off = (size_t)m * C_DIM + n;
                    out[off] = acc[fi][fj][r] + bn + query[off];
                }
            }
        }
    }
}

extern "C" void kernel_launch(void* const* d_in, const int* in_sizes, int n_in,
                              void* d_out, int out_size, void* d_ws, size_t ws_size,
                              hipStream_t stream) {
    const float* query = (const float*)d_in[0];   // (1, 10000, 256)
    const float* img   = (const float*)d_in[1];   // (1, 6, 256, 32, 88)
    const float* l2i   = (const float*)d_in[2];   // (1, 6, 4, 4)
    const float* Wout  = (const float*)d_in[3];   // (256, 256)
    const float* bout  = (const float*)d_in[4];   // (256,)
    float* out = (float*)d_out;

    // workspace layout (16B aligned)
    unsigned short* imgT = (unsigned short*)d_ws;                     // 6*2816*256*2 = 8,650,752 B
    unsigned short* wbuf = (unsigned short*)((char*)d_ws + 8650752);  // 10000*256*2  = 5,120,000 B

    dim3 gP(HW_IMG / 32, C_DIM / 64, N_CAM);   // (88, 4, 6)
    prep_kernel<<<gP, 256, 0, stream>>>(img, imgT);

    sample_kernel<<<NQ / 4, 256, 0, stream>>>(imgT, l2i, wbuf);

    dim3 gG((NQ + BM - 1) / BM, C_DIM / BN);   // (157, 4)
    gemm_kernel<<<gG, 256, 0, stream>>>(wbuf, Wout, bout, query, out);
}

// Round 10
// 28.666 us; speedup vs baseline: 2.8214x; 1.0409x over previous
//
#include <hip/hip_runtime.h>
#include <hip/hip_bf16.h>
#include <math.h>

#define BEV_H 100
#define BEV_W 100
#define BEV_Z 4
#define N_CAM 6
#define C_DIM 256
#define H_IMG 32
#define W_IMG 88
#define NQ (BEV_H * BEV_W)
#define HW_IMG (H_IMG * W_IMG)   // 2816

typedef float f32x4 __attribute__((ext_vector_type(4)));
typedef short short8 __attribute__((ext_vector_type(8)));

__device__ __forceinline__ unsigned short f2b(float f) {
    __hip_bfloat16 h = __float2bfloat16(f);   // RNE
    return *reinterpret_cast<unsigned short*>(&h);
}
__device__ __forceinline__ float b2f_lo(unsigned int u) {   // low ushort -> f32
    return __uint_as_float(u << 16);
}
__device__ __forceinline__ float b2f_hi(unsigned int u) {   // high ushort -> f32
    return __uint_as_float(u & 0xffff0000u);
}

// ---------------- Kernel 1: img (cam,C,H,W) f32 -> imgT (cam,HW,C) bf16; z==6: Wout f32 -> bf16
__global__ __launch_bounds__(256) void prep_kernel(const float* __restrict__ img,
                                                   const float* __restrict__ Wout,
                                                   unsigned short* __restrict__ imgT,
                                                   unsigned short* __restrict__ Woutb) {
    int cam = blockIdx.z;
    int t = threadIdx.x;
    if (cam == N_CAM) {
        if (blockIdx.y == 0 && blockIdx.x < 64) {
            int base = (blockIdx.x * 256 + t) * 4;
            float4 v = *(const float4*)(Wout + base);
            ushort4 o;
            o.x = f2b(v.x); o.y = f2b(v.y); o.z = f2b(v.z); o.w = f2b(v.w);
            *(ushort4*)(Woutb + base) = o;
        }
        return;
    }
    __shared__ unsigned short tile[32][68];   // [hw][c], pad 68 keeps ushort4 reads clean
    int hw0 = blockIdx.x * 32;                // 88 blocks
    int c0  = blockIdx.y * 64;                // 4 blocks
    const float* src = img + (size_t)cam * C_DIM * HW_IMG;
    #pragma unroll
    for (int i = 0; i < 2; ++i) {
        int e = i * 256 + t;                  // 0..511
        int c  = e >> 3;                      // 0..63
        int hq = e & 7;                       // hw quad
        float4 v = *(const float4*)(src + (size_t)(c0 + c) * HW_IMG + hw0 + hq * 4);
        tile[hq * 4 + 0][c] = f2b(v.x);
        tile[hq * 4 + 1][c] = f2b(v.y);
        tile[hq * 4 + 2][c] = f2b(v.z);
        tile[hq * 4 + 3][c] = f2b(v.w);
    }
    __syncthreads();
    unsigned short* dst = imgT + (size_t)cam * HW_IMG * C_DIM;
    #pragma unroll
    for (int i = 0; i < 2; ++i) {
        int e = i * 256 + t;
        int hw = e >> 4;                      // 0..31
        int cq = e & 15;                      // c quad
        ushort4 o;
        o.x = tile[hw][cq * 4 + 0];
        o.y = tile[hw][cq * 4 + 1];
        o.z = tile[hw][cq * 4 + 2];
        o.w = tile[hw][cq * 4 + 3];
        *(ushort4*)(dst + (size_t)(hw0 + hw) * C_DIM + c0 + cq * 4) = o;
    }
}

// ---------------- Kernel 2: project + bilinear + pool, two-phase, 8 queries/block.
// Phase 1: each of 256 threads projects one (q,slot); valid slots compacted
// into LDS via deterministic ballot-prefix (order preserved -> reproducible).
// Phase 2: each HALF-wave owns one query (8 ch/lane, 16B gathers); wave serves
// 2 queries. OOB corners: clamped offset, zero weight (== reference clip+mask).
__global__ __launch_bounds__(256) void sample_kernel(const unsigned short* __restrict__ imgT,
                                                     const float* __restrict__ l2i,
                                                     unsigned short* __restrict__ wbuf) {
    __shared__ int   ent_off[8][24][4];
    __shared__ float ent_w[8][24][4];
    __shared__ int   counts[8];
    int t = threadIdx.x;

    {
        int ql   = t >> 5;        // 0..7
        int slot = t & 31;        // 0..31; slots 24..31 padding
        int q = blockIdx.x * 8 + ql;
        int ix = q % BEV_W;
        int iy = q / BEV_W;
        float x = ((ix + 0.5f) / (float)BEV_W) * 102.4f - 51.2f;
        float y = ((iy + 0.5f) / (float)BEV_H) * 102.4f - 51.2f;

        bool valid = false;
        int   o0 = 0, o1 = 0, o2 = 0, o3 = 0;
        float w0 = 0.f, w1 = 0.f, w2 = 0.f, w3 = 0.f;
        if (slot < 24) {
            int cam = slot >> 2;
            int zi  = slot & 3;
            const float* L = l2i + cam * 16;
            float zl = (zi + 0.5f) * 8.0f - 5.0f;   // reference's unnormalized z
            float cx = fmaf(L[0], x, fmaf(L[1], y, fmaf(L[2],  zl, L[3])));
            float cy = fmaf(L[4], x, fmaf(L[5], y, fmaf(L[6],  zl, L[7])));
            float cz = fmaf(L[8], x, fmaf(L[9], y, fmaf(L[10], zl, L[11])));
            float denom = fmaxf(cz, 1e-5f);
            float inv = __builtin_amdgcn_rcpf(denom);
            float u = cx * inv;
            float v = cy * inv;
            if ((cz > 1e-5f) && (u > 0.f) && (u < (float)W_IMG)
                             && (v > 0.f) && (v < (float)H_IMG)) {
                valid = true;
                float xs = u - 0.5f;    // == (gx+1)*W/2 - 0.5 exactly
                float ys = v - 0.5f;
                float x0f = floorf(xs), y0f = floorf(ys);
                float wx1 = xs - x0f,   wy1 = ys - y0f;
                float wx0 = 1.0f - wx1, wy0 = 1.0f - wy1;
                int x0 = (int)x0f, y0 = (int)y0f;   // x0 in [-1,87], y0 in [-1,31]
                int x1 = x0 + 1,   y1 = y0 + 1;
                float mxl = (x0 >= 0)     ? 1.f : 0.f;
                float mxh = (x1 < W_IMG)  ? 1.f : 0.f;
                float myl = (y0 >= 0)     ? 1.f : 0.f;
                float myh = (y1 < H_IMG)  ? 1.f : 0.f;
                int x0c = max(x0, 0), x1c = min(x1, W_IMG - 1);
                int y0c = max(y0, 0), y1c = min(y1, H_IMG - 1);
                int cbase = cam * HW_IMG;
                // byte offsets into imgT (row stride C_DIM*2 = 512 = <<9)
                o0 = (cbase + y0c * W_IMG + x0c) << 9;  w0 = (wx0 * mxl) * (wy0 * myl);
                o1 = (cbase + y0c * W_IMG + x1c) << 9;  w1 = (wx1 * mxh) * (wy0 * myl);
                o2 = (cbase + y1c * W_IMG + x0c) << 9;  w2 = (wx0 * mxl) * (wy1 * myh);
                o3 = (cbase + y1c * W_IMG + x1c) << 9;  w3 = (wx1 * mxh) * (wy1 * myh);
            }
        }
        unsigned long long bal = __ballot(valid);
        unsigned int half = (t & 32) ? (unsigned int)(bal >> 32) : (unsigned int)bal;
        int lane32 = t & 31;
        int pre = __popc(half & ((1u << lane32) - 1u));
        if (valid) {
            ent_off[ql][pre][0] = o0; ent_off[ql][pre][1] = o1;
            ent_off[ql][pre][2] = o2; ent_off[ql][pre][3] = o3;
            ent_w[ql][pre][0] = w0; ent_w[ql][pre][1] = w1;
            ent_w[ql][pre][2] = w2; ent_w[ql][pre][3] = w3;
        }
        if (lane32 == 0) counts[ql] = __popc(half);
    }
    __syncthreads();

    int qi = t >> 5;               // 0..7: half-wave index == query index
    int lane32 = t & 31;
    int q = blockIdx.x * 8 + qi;
    int cnt = counts[qi];
    const char* base = (const char*)imgT + lane32 * 16;   // 8 channels/lane

    float a0 = 0.f, a1 = 0.f, a2 = 0.f, a3 = 0.f;
    float a4 = 0.f, a5 = 0.f, a6 = 0.f, a7 = 0.f;
    for (int i = 0; i < cnt; ++i) {   // divergent between halves; exec-masked
        int4   offs = *(const int4*)(&ent_off[qi][i][0]);    // broadcast/half
        float4 wv   = *(const float4*)(&ent_w[qi][i][0]);
        int4 f0 = *(const int4*)(base + offs.x);
        int4 f1 = *(const int4*)(base + offs.y);
        int4 f2 = *(const int4*)(base + offs.z);
        int4 f3 = *(const int4*)(base + offs.w);
        a0 += b2f_lo(f0.x) * wv.x; a1 += b2f_hi(f0.x) * wv.x;
        a2 += b2f_lo(f0.y) * wv.x; a3 += b2f_hi(f0.y) * wv.x;
        a4 += b2f_lo(f0.z) * wv.x; a5 += b2f_hi(f0.z) * wv.x;
        a6 += b2f_lo(f0.w) * wv.x; a7 += b2f_hi(f0.w) * wv.x;
        a0 += b2f_lo(f1.x) * wv.y; a1 += b2f_hi(f1.x) * wv.y;
        a2 += b2f_lo(f1.y) * wv.y; a3 += b2f_hi(f1.y) * wv.y;
        a4 += b2f_lo(f1.z) * wv.y; a5 += b2f_hi(f1.z) * wv.y;
        a6 += b2f_lo(f1.w) * wv.y; a7 += b2f_hi(f1.w) * wv.y;
        a0 += b2f_lo(f2.x) * wv.z; a1 += b2f_hi(f2.x) * wv.z;
        a2 += b2f_lo(f2.y) * wv.z; a3 += b2f_hi(f2.y) * wv.z;
        a4 += b2f_lo(f2.z) * wv.z; a5 += b2f_hi(f2.z) * wv.z;
        a6 += b2f_lo(f2.w) * wv.z; a7 += b2f_hi(f2.w) * wv.z;
        a0 += b2f_lo(f3.x) * wv.w; a1 += b2f_hi(f3.x) * wv.w;
        a2 += b2f_lo(f3.y) * wv.w; a3 += b2f_hi(f3.y) * wv.w;
        a4 += b2f_lo(f3.z) * wv.w; a5 += b2f_hi(f3.z) * wv.w;
        a6 += b2f_lo(f3.w) * wv.w; a7 += b2f_hi(f3.w) * wv.w;
    }
    const float s = 1.0f / 24.0f;
    int4 o;
    o.x = (int)f2b(a0 * s) | ((int)f2b(a1 * s) << 16);
    o.y = (int)f2b(a2 * s) | ((int)f2b(a3 * s) << 16);
    o.z = (int)f2b(a4 * s) | ((int)f2b(a5 * s) << 16);
    o.w = (int)f2b(a6 * s) | ((int)f2b(a7 * s) << 16);
    *(int4*)(wbuf + (size_t)q * C_DIM + lane32 * 8) = o;
}

// ---------------- Kernel 3: out = w @ Wout^T + b + query, bf16 MFMA 16x16x32
// Block 64x64, 4 waves 2x2. BK=128 (2 stages), XOR-swizzled LDS (T2), 4 barriers.
// B now read from precomputed bf16 Woutb (int4 path, no per-block cvt).
#define BM 64
#define BN 64
#define BKK 128
__global__ __launch_bounds__(256) void gemm_kernel(const unsigned short* __restrict__ A,   // wbuf bf16 (NQ x 256)
                                                   const unsigned short* __restrict__ B,   // Woutb bf16 (256 x 256)
                                                   const float* __restrict__ bout,
                                                   const float* __restrict__ query,
                                                   float* __restrict__ out) {
    __shared__ unsigned short Al[BM * BKK];   // 16 KB, swizzled: byte ^= (row&7)<<4
    __shared__ unsigned short Bl[BN * BKK];   // 16 KB
    int rb = blockIdx.x * BM;
    int cb = blockIdx.y * BN;
    int t = threadIdx.x;
    int lane = t & 63;
    int wid = t >> 6;
    int wr = wid >> 1, wc = wid & 1;
    int fr = lane & 15;
    int kq = lane >> 4;                       // 0..3: k-group within K=32

    f32x4 acc[2][2] = {};

    for (int kt = 0; kt < C_DIM; kt += BKK) {
        // stage A + B: 64 rows x 128 k (bf16) = 1024 x 16B chunks each
        #pragma unroll
        for (int i = 0; i < 4; ++i) {
            int idx = i * 256 + t;            // 0..1023
            int row = idx >> 4;               // 0..63
            int ch  = idx & 15;               // 16B chunk within 256B row
            int4 av = make_int4(0, 0, 0, 0);
            int grow = rb + row;
            if (grow < NQ) av = *(const int4*)(A + (size_t)grow * C_DIM + kt + ch * 8);
            int4 bv = *(const int4*)(B + (size_t)(cb + row) * C_DIM + kt + ch * 8);
            int off = (row * 256 + ch * 16) ^ ((row & 7) << 4);
            *(int4*)((char*)Al + off) = av;
            *(int4*)((char*)Bl + off) = bv;
        }
        __syncthreads();

        #pragma unroll
        for (int ks = 0; ks < 4; ++ks) {
            int kbyte = ks * 64 + kq * 16;
            int ra0 = wr * 32 + fr, ra1 = ra0 + 16;
            int rb0 = wc * 32 + fr, rb1 = rb0 + 16;
            short8 af0 = *(const short8*)((const char*)Al + ((ra0 * 256 + kbyte) ^ ((ra0 & 7) << 4)));
            short8 af1 = *(const short8*)((const char*)Al + ((ra1 * 256 + kbyte) ^ ((ra1 & 7) << 4)));
            short8 bf0 = *(const short8*)((const char*)Bl + ((rb0 * 256 + kbyte) ^ ((rb0 & 7) << 4)));
            short8 bf1 = *(const short8*)((const char*)Bl + ((rb1 * 256 + kbyte) ^ ((rb1 & 7) << 4)));
            acc[0][0] = __builtin_amdgcn_mfma_f32_16x16x32_bf16(af0, bf0, acc[0][0], 0, 0, 0);
            acc[0][1] = __builtin_amdgcn_mfma_f32_16x16x32_bf16(af0, bf1, acc[0][1], 0, 0, 0);
            acc[1][0] = __builtin_amdgcn_mfma_f32_16x16x32_bf16(af1, bf0, acc[1][0], 0, 0, 0);
            acc[1][1] = __builtin_amdgcn_mfma_f32_16x16x32_bf16(af1, bf1, acc[1][1], 0, 0, 0);
        }
        __syncthreads();
    }

    // C/D layout (verified m89/m91): col = lane&15, row = (lane>>4)*4 + reg
    int crow = (lane >> 4) * 4;
    int ccol = lane & 15;
    #pragma unroll
    for (int fi = 0; fi < 2; ++fi) {
        #pragma unroll
        for (int fj = 0; fj < 2; ++fj) {
            int n = cb + wc * 32 + fj * 16 + ccol;
            float bn = bout[n];
            #pragma unroll
            for (int r = 0; r < 4; ++r) {
                int m = rb + wr * 32 + fi * 16 + crow + r;
                if (m < NQ) {
                    size_t off = (size_t)m * C_DIM + n;
                    out[off] = acc[fi][fj][r] + bn + query[off];
                }
            }
        }
    }
}

extern "C" void kernel_launch(void* const* d_in, const int* in_sizes, int n_in,
                              void* d_out, int out_size, void* d_ws, size_t ws_size,
                              hipStream_t stream) {
    const float* query = (const float*)d_in[0];   // (1, 10000, 256)
    const float* img   = (const float*)d_in[1];   // (1, 6, 256, 32, 88)
    const float* l2i   = (const float*)d_in[2];   // (1, 6, 4, 4)
    const float* Wout  = (const float*)d_in[3];   // (256, 256)
    const float* bout  = (const float*)d_in[4];   // (256,)
    float* out = (float*)d_out;

    // workspace layout (16B aligned)
    unsigned short* imgT  = (unsigned short*)d_ws;                       // 6*2816*256*2 = 8,650,752 B
    unsigned short* wbuf  = (unsigned short*)((char*)d_ws + 8650752);    // 10000*256*2  = 5,120,000 B
    unsigned short* Woutb = (unsigned short*)((char*)d_ws + 13770752);   // 256*256*2    =   131,072 B

    dim3 gP(HW_IMG / 32, C_DIM / 64, N_CAM + 1);   // (88, 4, 7); z==6 converts Wout
    prep_kernel<<<gP, 256, 0, stream>>>(img, Wout, imgT, Woutb);

    sample_kernel<<<NQ / 8, 256, 0, stream>>>(imgT, l2i, wbuf);   // 1250 blocks

    dim3 gG((NQ + BM - 1) / BM, C_DIM / BN);       // (157, 4)
    gemm_kernel<<<gG, 256, 0, stream>>>(wbuf, Woutb, bout, query, out);
}

// Round 11
// 27.947 us; speedup vs baseline: 2.8940x; 1.0257x over previous
//
#include <hip/hip_runtime.h>
#include <hip/hip_bf16.h>
#include <math.h>

#define BEV_H 100
#define BEV_W 100
#define BEV_Z 4
#define N_CAM 6
#define C_DIM 256
#define H_IMG 32
#define W_IMG 88
#define NQ (BEV_H * BEV_W)
#define HW_IMG (H_IMG * W_IMG)   // 2816

typedef float f32x4 __attribute__((ext_vector_type(4)));
typedef short short8 __attribute__((ext_vector_type(8)));

__device__ __forceinline__ unsigned short f2b(float f) {
    __hip_bfloat16 h = __float2bfloat16(f);   // RNE
    return *reinterpret_cast<unsigned short*>(&h);
}
__device__ __forceinline__ float b2f_lo(unsigned int u) {   // low ushort -> f32
    return __uint_as_float(u << 16);
}
__device__ __forceinline__ float b2f_hi(unsigned int u) {   // high ushort -> f32
    return __uint_as_float(u & 0xffff0000u);
}

// Bijective XCD-chunked blockIdx swizzle (m204): consecutive returned ids are
// processed by the same XCD (dispatch round-robins blockIdx across 8 XCDs).
__device__ __forceinline__ int xcd_swz(int bid, int nwg) {
    int q = nwg >> 3, r = nwg & 7;
    int xcd = bid & 7;
    int idx = bid >> 3;
    int base = (xcd < r) ? xcd * (q + 1) : r * (q + 1) + (xcd - r) * q;
    return base + idx;
}

// ---------------- Kernel 1: img (cam,C,H,W) f32 -> imgT (cam,HW,C) bf16; z==6: Wout f32 -> bf16
__global__ __launch_bounds__(256) void prep_kernel(const float* __restrict__ img,
                                                   const float* __restrict__ Wout,
                                                   unsigned short* __restrict__ imgT,
                                                   unsigned short* __restrict__ Woutb) {
    int cam = blockIdx.z;
    int t = threadIdx.x;
    if (cam == N_CAM) {
        if (blockIdx.y == 0 && blockIdx.x < 64) {
            int base = (blockIdx.x * 256 + t) * 4;
            float4 v = *(const float4*)(Wout + base);
            ushort4 o;
            o.x = f2b(v.x); o.y = f2b(v.y); o.z = f2b(v.z); o.w = f2b(v.w);
            *(ushort4*)(Woutb + base) = o;
        }
        return;
    }
    __shared__ unsigned short tile[32][68];   // [hw][c], pad 68 keeps ushort4 reads clean
    int hw0 = blockIdx.x * 32;                // 88 blocks
    int c0  = blockIdx.y * 64;                // 4 blocks
    const float* src = img + (size_t)cam * C_DIM * HW_IMG;
    #pragma unroll
    for (int i = 0; i < 2; ++i) {
        int e = i * 256 + t;                  // 0..511
        int c  = e >> 3;                      // 0..63
        int hq = e & 7;                       // hw quad
        float4 v = *(const float4*)(src + (size_t)(c0 + c) * HW_IMG + hw0 + hq * 4);
        tile[hq * 4 + 0][c] = f2b(v.x);
        tile[hq * 4 + 1][c] = f2b(v.y);
        tile[hq * 4 + 2][c] = f2b(v.z);
        tile[hq * 4 + 3][c] = f2b(v.w);
    }
    __syncthreads();
    unsigned short* dst = imgT + (size_t)cam * HW_IMG * C_DIM;
    #pragma unroll
    for (int i = 0; i < 2; ++i) {
        int e = i * 256 + t;
        int hw = e >> 4;                      // 0..31
        int cq = e & 15;                      // c quad
        ushort4 o;
        o.x = tile[hw][cq * 4 + 0];
        o.y = tile[hw][cq * 4 + 1];
        o.z = tile[hw][cq * 4 + 2];
        o.w = tile[hw][cq * 4 + 3];
        *(ushort4*)(dst + (size_t)(hw0 + hw) * C_DIM + c0 + cq * 4) = o;
    }
}

// ---------------- Kernel 2: project + bilinear + pool, two-phase, 8 queries/block.
// XCD-chunked swizzle: contiguous q ranges -> same XCD L2 (texel arc ~2MB fits 4MB).
__global__ __launch_bounds__(256) void sample_kernel(const unsigned short* __restrict__ imgT,
                                                     const float* __restrict__ l2i,
                                                     unsigned short* __restrict__ wbuf) {
    __shared__ int   ent_off[8][24][4];
    __shared__ float ent_w[8][24][4];
    __shared__ int   counts[8];
    int t = threadIdx.x;
    int blk = xcd_swz(blockIdx.x, NQ / 8);   // 1250 blocks

    {
        int ql   = t >> 5;        // 0..7
        int slot = t & 31;        // 0..31; slots 24..31 padding
        int q = blk * 8 + ql;
        int ix = q % BEV_W;
        int iy = q / BEV_W;
        float x = ((ix + 0.5f) / (float)BEV_W) * 102.4f - 51.2f;
        float y = ((iy + 0.5f) / (float)BEV_H) * 102.4f - 51.2f;

        bool valid = false;
        int   o0 = 0, o1 = 0, o2 = 0, o3 = 0;
        float w0 = 0.f, w1 = 0.f, w2 = 0.f, w3 = 0.f;
        if (slot < 24) {
            int cam = slot >> 2;
            int zi  = slot & 3;
            const float* L = l2i + cam * 16;
            float zl = (zi + 0.5f) * 8.0f - 5.0f;   // reference's unnormalized z
            float cx = fmaf(L[0], x, fmaf(L[1], y, fmaf(L[2],  zl, L[3])));
            float cy = fmaf(L[4], x, fmaf(L[5], y, fmaf(L[6],  zl, L[7])));
            float cz = fmaf(L[8], x, fmaf(L[9], y, fmaf(L[10], zl, L[11])));
            float denom = fmaxf(cz, 1e-5f);
            float inv = __builtin_amdgcn_rcpf(denom);
            float u = cx * inv;
            float v = cy * inv;
            if ((cz > 1e-5f) && (u > 0.f) && (u < (float)W_IMG)
                             && (v > 0.f) && (v < (float)H_IMG)) {
                valid = true;
                float xs = u - 0.5f;    // == (gx+1)*W/2 - 0.5 exactly
                float ys = v - 0.5f;
                float x0f = floorf(xs), y0f = floorf(ys);
                float wx1 = xs - x0f,   wy1 = ys - y0f;
                float wx0 = 1.0f - wx1, wy0 = 1.0f - wy1;
                int x0 = (int)x0f, y0 = (int)y0f;   // x0 in [-1,87], y0 in [-1,31]
                int x1 = x0 + 1,   y1 = y0 + 1;
                float mxl = (x0 >= 0)     ? 1.f : 0.f;
                float mxh = (x1 < W_IMG)  ? 1.f : 0.f;
                float myl = (y0 >= 0)     ? 1.f : 0.f;
                float myh = (y1 < H_IMG)  ? 1.f : 0.f;
                int x0c = max(x0, 0), x1c = min(x1, W_IMG - 1);
                int y0c = max(y0, 0), y1c = min(y1, H_IMG - 1);
                int cbase = cam * HW_IMG;
                // byte offsets into imgT (row stride C_DIM*2 = 512 = <<9)
                o0 = (cbase + y0c * W_IMG + x0c) << 9;  w0 = (wx0 * mxl) * (wy0 * myl);
                o1 = (cbase + y0c * W_IMG + x1c) << 9;  w1 = (wx1 * mxh) * (wy0 * myl);
                o2 = (cbase + y1c * W_IMG + x0c) << 9;  w2 = (wx0 * mxl) * (wy1 * myh);
                o3 = (cbase + y1c * W_IMG + x1c) << 9;  w3 = (wx1 * mxh) * (wy1 * myh);
            }
        }
        unsigned long long bal = __ballot(valid);
        unsigned int half = (t & 32) ? (unsigned int)(bal >> 32) : (unsigned int)bal;
        int lane32 = t & 31;
        int pre = __popc(half & ((1u << lane32) - 1u));
        if (valid) {
            ent_off[ql][pre][0] = o0; ent_off[ql][pre][1] = o1;
            ent_off[ql][pre][2] = o2; ent_off[ql][pre][3] = o3;
            ent_w[ql][pre][0] = w0; ent_w[ql][pre][1] = w1;
            ent_w[ql][pre][2] = w2; ent_w[ql][pre][3] = w3;
        }
        if (lane32 == 0) counts[ql] = __popc(half);
    }
    __syncthreads();

    int qi = t >> 5;               // 0..7: half-wave index == query index
    int lane32 = t & 31;
    int q = blk * 8 + qi;
    int cnt = counts[qi];
    const char* base = (const char*)imgT + lane32 * 16;   // 8 channels/lane

    float a0 = 0.f, a1 = 0.f, a2 = 0.f, a3 = 0.f;
    float a4 = 0.f, a5 = 0.f, a6 = 0.f, a7 = 0.f;
    for (int i = 0; i < cnt; ++i) {   // divergent between halves; exec-masked
        int4   offs = *(const int4*)(&ent_off[qi][i][0]);    // broadcast/half
        float4 wv   = *(const float4*)(&ent_w[qi][i][0]);
        int4 f0 = *(const int4*)(base + offs.x);
        int4 f1 = *(const int4*)(base + offs.y);
        int4 f2 = *(const int4*)(base + offs.z);
        int4 f3 = *(const int4*)(base + offs.w);
        a0 += b2f_lo(f0.x) * wv.x; a1 += b2f_hi(f0.x) * wv.x;
        a2 += b2f_lo(f0.y) * wv.x; a3 += b2f_hi(f0.y) * wv.x;
        a4 += b2f_lo(f0.z) * wv.x; a5 += b2f_hi(f0.z) * wv.x;
        a6 += b2f_lo(f0.w) * wv.x; a7 += b2f_hi(f0.w) * wv.x;
        a0 += b2f_lo(f1.x) * wv.y; a1 += b2f_hi(f1.x) * wv.y;
        a2 += b2f_lo(f1.y) * wv.y; a3 += b2f_hi(f1.y) * wv.y;
        a4 += b2f_lo(f1.z) * wv.y; a5 += b2f_hi(f1.z) * wv.y;
        a6 += b2f_lo(f1.w) * wv.y; a7 += b2f_hi(f1.w) * wv.y;
        a0 += b2f_lo(f2.x) * wv.z; a1 += b2f_hi(f2.x) * wv.z;
        a2 += b2f_lo(f2.y) * wv.z; a3 += b2f_hi(f2.y) * wv.z;
        a4 += b2f_lo(f2.z) * wv.z; a5 += b2f_hi(f2.z) * wv.z;
        a6 += b2f_lo(f2.w) * wv.z; a7 += b2f_hi(f2.w) * wv.z;
        a0 += b2f_lo(f3.x) * wv.w; a1 += b2f_hi(f3.x) * wv.w;
        a2 += b2f_lo(f3.y) * wv.w; a3 += b2f_hi(f3.y) * wv.w;
        a4 += b2f_lo(f3.z) * wv.w; a5 += b2f_hi(f3.z) * wv.w;
        a6 += b2f_lo(f3.w) * wv.w; a7 += b2f_hi(f3.w) * wv.w;
    }
    const float s = 1.0f / 24.0f;
    int4 o;
    o.x = (int)f2b(a0 * s) | ((int)f2b(a1 * s) << 16);
    o.y = (int)f2b(a2 * s) | ((int)f2b(a3 * s) << 16);
    o.z = (int)f2b(a4 * s) | ((int)f2b(a5 * s) << 16);
    o.w = (int)f2b(a6 * s) | ((int)f2b(a7 * s) << 16);
    *(int4*)(wbuf + (size_t)q * C_DIM + lane32 * 8) = o;
}

// ---------------- Kernel 3: out = w @ Wout^T + b + query, bf16 MFMA 16x16x32
// 1-D grid 628 = 157 row-tiles x 4 col-tiles (row-major), XCD-chunked swizzle
// so the 4 col-tiles of a row-tile land on one XCD (A-row L2 reuse).
#define BM 64
#define BN 64
#define BKK 128
__global__ __launch_bounds__(256) void gemm_kernel(const unsigned short* __restrict__ A,   // wbuf bf16 (NQ x 256)
                                                   const unsigned short* __restrict__ B,   // Woutb bf16 (256 x 256)
                                                   const float* __restrict__ bout,
                                                   const float* __restrict__ query,
                                                   float* __restrict__ out) {
    __shared__ unsigned short Al[BM * BKK];   // 16 KB, swizzled: byte ^= (row&7)<<4
    __shared__ unsigned short Bl[BN * BKK];   // 16 KB
    int blk = xcd_swz(blockIdx.x, 157 * 4);
    int rb = (blk >> 2) * BM;
    int cb = (blk & 3) * BN;
    int t = threadIdx.x;
    int lane = t & 63;
    int wid = t >> 6;
    int wr = wid >> 1, wc = wid & 1;
    int fr = lane & 15;
    int kq = lane >> 4;                       // 0..3: k-group within K=32

    f32x4 acc[2][2] = {};

    for (int kt = 0; kt < C_DIM; kt += BKK) {
        // stage A + B: 64 rows x 128 k (bf16) = 1024 x 16B chunks each
        #pragma unroll
        for (int i = 0; i < 4; ++i) {
            int idx = i * 256 + t;            // 0..1023
            int row = idx >> 4;               // 0..63
            int ch  = idx & 15;               // 16B chunk within 256B row
            int4 av = make_int4(0, 0, 0, 0);
            int grow = rb + row;
            if (grow < NQ) av = *(const int4*)(A + (size_t)grow * C_DIM + kt + ch * 8);
            int4 bv = *(const int4*)(B + (size_t)(cb + row) * C_DIM + kt + ch * 8);
            int off = (row * 256 + ch * 16) ^ ((row & 7) << 4);
            *(int4*)((char*)Al + off) = av;
            *(int4*)((char*)Bl + off) = bv;
        }
        __syncthreads();

        #pragma unroll
        for (int ks = 0; ks < 4; ++ks) {
            int kbyte = ks * 64 + kq * 16;
            int ra0 = wr * 32 + fr, ra1 = ra0 + 16;
            int rb0 = wc * 32 + fr, rb1 = rb0 + 16;
            short8 af0 = *(const short8*)((const char*)Al + ((ra0 * 256 + kbyte) ^ ((ra0 & 7) << 4)));
            short8 af1 = *(const short8*)((const char*)Al + ((ra1 * 256 + kbyte) ^ ((ra1 & 7) << 4)));
            short8 bf0 = *(const short8*)((const char*)Bl + ((rb0 * 256 + kbyte) ^ ((rb0 & 7) << 4)));
            short8 bf1 = *(const short8*)((const char*)Bl + ((rb1 * 256 + kbyte) ^ ((rb1 & 7) << 4)));
            acc[0][0] = __builtin_amdgcn_mfma_f32_16x16x32_bf16(af0, bf0, acc[0][0], 0, 0, 0);
            acc[0][1] = __builtin_amdgcn_mfma_f32_16x16x32_bf16(af0, bf1, acc[0][1], 0, 0, 0);
            acc[1][0] = __builtin_amdgcn_mfma_f32_16x16x32_bf16(af1, bf0, acc[1][0], 0, 0, 0);
            acc[1][1] = __builtin_amdgcn_mfma_f32_16x16x32_bf16(af1, bf1, acc[1][1], 0, 0, 0);
        }
        __syncthreads();
    }

    // C/D layout (verified m89/m91): col = lane&15, row = (lane>>4)*4 + reg
    int crow = (lane >> 4) * 4;
    int ccol = lane & 15;
    #pragma unroll
    for (int fi = 0; fi < 2; ++fi) {
        #pragma unroll
        for (int fj = 0; fj < 2; ++fj) {
            int n = cb + wc * 32 + fj * 16 + ccol;
            float bn = bout[n];
            #pragma unroll
            for (int r = 0; r < 4; ++r) {
                int m = rb + wr * 32 + fi * 16 + crow + r;
                if (m < NQ) {
                    size_t off = (size_t)m * C_DIM + n;
                    out[off] = acc[fi][fj][r] + bn + query[off];
                }
            }
        }
    }
}

extern "C" void kernel_launch(void* const* d_in, const int* in_sizes, int n_in,
                              void* d_out, int out_size, void* d_ws, size_t ws_size,
                              hipStream_t stream) {
    const float* query = (const float*)d_in[0];   // (1, 10000, 256)
    const float* img   = (const float*)d_in[1];   // (1, 6, 256, 32, 88)
    const float* l2i   = (const float*)d_in[2];   // (1, 6, 4, 4)
    const float* Wout  = (const float*)d_in[3];   // (256, 256)
    const float* bout  = (const float*)d_in[4];   // (256,)
    float* out = (float*)d_out;

    // workspace layout (16B aligned)
    unsigned short* imgT  = (unsigned short*)d_ws;                       // 6*2816*256*2 = 8,650,752 B
    unsigned short* wbuf  = (unsigned short*)((char*)d_ws + 8650752);    // 10000*256*2  = 5,120,000 B
    unsigned short* Woutb = (unsigned short*)((char*)d_ws + 13770752);   // 256*256*2    =   131,072 B

    dim3 gP(HW_IMG / 32, C_DIM / 64, N_CAM + 1);   // (88, 4, 7); z==6 converts Wout
    prep_kernel<<<gP, 256, 0, stream>>>(img, Wout, imgT, Woutb);

    sample_kernel<<<NQ / 8, 256, 0, stream>>>(imgT, l2i, wbuf);   // 1250 blocks

    gemm_kernel<<<157 * 4, 256, 0, stream>>>(wbuf, Woutb, bout, query, out);
}